// Round 1
// baseline (133.263 us; speedup 1.0000x reference)
//
#include <hip/hip_runtime.h>

#define BSZ 8
#define NQ 2048
#define MP 64
#define DD 1024
#define BN 64        // query rows per block
#define BK 64        // d elements per K chunk
#define K2 128       // 2*BK interleaved bf16 k-extent
#define LDK 136      // K2 + 8 pad (breaks b128 bank conflicts)
#define KT 16        // DD / BK

typedef __bf16 bf16x8 __attribute__((ext_vector_type(8)));
typedef float f32x4 __attribute__((ext_vector_type(4)));
typedef unsigned short us8 __attribute__((ext_vector_type(8)));

__device__ __forceinline__ unsigned short f2bf(float f) {
    union { float f; unsigned int u; } v; v.f = f;
    unsigned int u = v.u;
    return (unsigned short)((u + 0x7FFFu + ((u >> 16) & 1u)) >> 16);  // RNE
}

__global__ __launch_bounds__(256) void proto_head_kernel(
    const float* __restrict__ proto,
    const float* __restrict__ mask,
    const float* __restrict__ query,
    const float* __restrict__ scale,
    float* __restrict__ out)
{
    __shared__ unsigned short Qs[BN][LDK];   // k even: q^2, k odd: q
    __shared__ unsigned short Ps[MP][LDK];   // k even: mask^2, k odd: -2*mask^2*p
    __shared__ float Pterm[MP];

    const int tid = threadIdx.x;
    const int bid = blockIdx.x;
    const int b  = bid & 7;            // batch = bid % 8 -> XCD-affine proto reuse
    const int n0 = (bid >> 3) * BN;

    if (tid < MP) Pterm[tid] = 0.0f;

    // Q staging map: 16 rows/pass x 16 float4 cols
    const int qr = tid >> 4;           // 0..15
    const int qc = tid & 15;           // 0..15
    // P staging map: 4 threads per m-row (fixed m per thread for pterm)
    const int pm = tid >> 2;           // 0..63
    const int pc = tid & 3;            // 0..3

    const float* qbase = query + ((size_t)b * NQ + n0) * DD;
    const float* mrow  = mask  + ((size_t)(b * MP + pm)) * DD;
    const float* prow  = proto + ((size_t)(b * MP + pm)) * DD;

    const int lane = tid & 63;
    const int wid  = tid >> 6;
    const int lrow = lane & 15;
    const int lq8  = (lane >> 4) * 8;

    f32x4 acc[4];
    acc[0] = acc[1] = acc[2] = acc[3] = (f32x4){0.f, 0.f, 0.f, 0.f};
    float pacc = 0.f;

    float4 qv[4], mv[4], pv[4];

    // prefetch chunk 0
    {
        #pragma unroll
        for (int p = 0; p < 4; ++p)
            qv[p] = *(const float4*)(qbase + (size_t)(qr + 16 * p) * DD + 4 * qc);
        #pragma unroll
        for (int p = 0; p < 4; ++p) {
            const int d4 = pc + 4 * p;
            mv[p] = *(const float4*)(mrow + 4 * d4);
            pv[p] = *(const float4*)(prow + 4 * d4);
        }
    }

    for (int kt = 0; kt < KT; ++kt) {
        // ---- store staged chunk to LDS (implicit vmcnt wait on prefetch) ----
        #pragma unroll
        for (int p = 0; p < 4; ++p) {
            const float4 q = qv[p];
            us8 o;
            o[0] = f2bf(q.x * q.x); o[1] = f2bf(q.x);
            o[2] = f2bf(q.y * q.y); o[3] = f2bf(q.y);
            o[4] = f2bf(q.z * q.z); o[5] = f2bf(q.z);
            o[6] = f2bf(q.w * q.w); o[7] = f2bf(q.w);
            *(us8*)(&Qs[qr + 16 * p][8 * qc]) = o;
        }
        #pragma unroll
        for (int p = 0; p < 4; ++p) {
            const int d4 = pc + 4 * p;
            const float4 mk = mv[p], pr = pv[p];
            const float m2x = mk.x * mk.x, m2y = mk.y * mk.y,
                        m2z = mk.z * mk.z, m2w = mk.w * mk.w;
            const float ax = mk.x * pr.x, ay = mk.y * pr.y,
                        az = mk.z * pr.z, aw = mk.w * pr.w;
            pacc += ax * ax + ay * ay + az * az + aw * aw;
            us8 o;
            o[0] = f2bf(m2x); o[1] = f2bf(-2.f * m2x * pr.x);
            o[2] = f2bf(m2y); o[3] = f2bf(-2.f * m2y * pr.y);
            o[4] = f2bf(m2z); o[5] = f2bf(-2.f * m2z * pr.z);
            o[6] = f2bf(m2w); o[7] = f2bf(-2.f * m2w * pr.w);
            *(us8*)(&Ps[pm][8 * d4]) = o;
        }
        __syncthreads();

        // ---- issue prefetch for next chunk (overlaps MFMA phase) ----
        if (kt + 1 < KT) {
            const float* qp = qbase + (kt + 1) * BK;
            #pragma unroll
            for (int p = 0; p < 4; ++p)
                qv[p] = *(const float4*)(qp + (size_t)(qr + 16 * p) * DD + 4 * qc);
            const float* mp2 = mrow + (kt + 1) * BK;
            const float* pp2 = prow + (kt + 1) * BK;
            #pragma unroll
            for (int p = 0; p < 4; ++p) {
                const int d4 = pc + 4 * p;
                mv[p] = *(const float4*)(mp2 + 4 * d4);
                pv[p] = *(const float4*)(pp2 + 4 * d4);
            }
        }

        // ---- MFMA over this chunk: wave wid handles n-rows [16*wid, 16*wid+16) ----
        #pragma unroll
        for (int k0 = 0; k0 < K2; k0 += 32) {
            const bf16x8 a = *(const bf16x8*)(&Qs[16 * wid + lrow][k0 + lq8]);
            #pragma unroll
            for (int mi = 0; mi < 4; ++mi) {
                const bf16x8 bb = *(const bf16x8*)(&Ps[16 * mi + lrow][k0 + lq8]);
                acc[mi] = __builtin_amdgcn_mfma_f32_16x16x32_bf16(a, bb, acc[mi], 0, 0, 0);
            }
        }
        __syncthreads();
    }

    // ---- pterm reduction (4 threads per m) ----
    atomicAdd(&Pterm[pm], pacc);
    __syncthreads();

    // ---- epilogue: out = scale * (acc + pterm) / D ----
    const float sc = scale[0] * (1.0f / (float)DD);
    #pragma unroll
    for (int mi = 0; mi < 4; ++mi) {
        const int m = 16 * mi + lrow;
        const float pt = Pterm[m];
        const size_t obase =
            ((size_t)b * NQ + (size_t)(n0 + 16 * wid + (lane >> 4) * 4)) * MP + m;
        #pragma unroll
        for (int r = 0; r < 4; ++r)
            out[obase + (size_t)r * MP] = (acc[mi][r] + pt) * sc;
    }
}

extern "C" void kernel_launch(void* const* d_in, const int* in_sizes, int n_in,
                              void* d_out, int out_size, void* d_ws, size_t ws_size,
                              hipStream_t stream) {
    (void)in_sizes; (void)n_in; (void)d_ws; (void)ws_size; (void)out_size;
    const float* proto = (const float*)d_in[0];
    const float* mask  = (const float*)d_in[1];
    const float* query = (const float*)d_in[2];
    // d_in[3] support, d_in[4] support_labels, d_in[6] n_way, d_in[7] n_shot: unused
    const float* scale = (const float*)d_in[5];
    float* out = (float*)d_out;

    dim3 grid(BSZ * (NQ / BN));  // 256 blocks: (batch = bid%8, ntile = bid/8)
    proto_head_kernel<<<grid, dim3(256), 0, stream>>>(proto, mask, query, scale, out);
}